// Round 1
// baseline (512.267 us; speedup 1.0000x reference)
//
#include <hip/hip_runtime.h>
#include <hip/hip_bf16.h>
#include <stdint.h>

#define Mdim 8192
#define KSTEPS 256   // 8192 / 32

typedef __attribute__((ext_vector_type(8))) short short8v;  // 8 bf16 (4 VGPRs)
typedef __attribute__((ext_vector_type(4))) float f32x4;

// round-to-nearest-even f32 -> bf16 (finite inputs)
static __device__ __forceinline__ short bf16r(float f) {
  union { float f; uint32_t u; } c; c.f = f;
  uint32_t u = c.u;
  uint32_t r = (u + 0x7fffu + ((u >> 16) & 1u)) >> 16;
  return (short)(r & 0xffffu);
}

// Repack x (f32 [8192][32]) into MFMA B-fragment layout:
// Bp[((ks*2 + h)*64 + lane)*8 + j] = bf16( B[ks*32 + (lane>>4)*8 + j][h*16 + (lane&15)] )
__global__ __launch_bounds__(256)
void repack_x(const float* __restrict__ x, short* __restrict__ Bp)
{
  int t = blockIdx.x * 256 + threadIdx.x;       // 32768 threads total
  int l = t & 63, h = (t >> 6) & 1, ks = t >> 7;
  int col = h * 16 + (l & 15);
  int kbase = ks * 32 + ((l >> 4) << 3);
  short8v v;
#pragma unroll
  for (int j = 0; j < 8; ++j) v[j] = bf16r(x[(size_t)(kbase + j) * 32 + col]);
  reinterpret_cast<short8v*>(Bp)[t] = v;
}

// One Chebyshev GEMM pass: Tout = alpha * (A @ B) + beta * Tprev
//   alpha=1,beta=0 (HASPREV=0)  or  alpha=2,beta=-1 (HASPREV=1)
// A: [8192][8192] f32 (ABF16=0) or bf16-as-short (ABF16=1), row-major.
// B: fragment-packed bf16 (see repack_x).
// Also emits BpOut = fragment-packed bf16 of Tout (next pass's B input),
// and (WRITE_AB) a bf16 copy of A for later passes.
// Grid: 512 blocks x 64 threads (1 wave = 16 output rows x 32 cols).
template<int ABF16, int WRITE_AB, int HASPREV>
__global__ __launch_bounds__(64)
void gemm_pass(const void* __restrict__ Av,
               short* __restrict__ AbOut,
               const short8v* __restrict__ Bp,
               const float* __restrict__ Tprev,
               float* __restrict__ Tout,
               short* __restrict__ BpOut)
{
  const int lane = threadIdx.x;
  const int r0 = blockIdx.x << 4;          // first output row of this wave
  const int arow = r0 + (lane & 15);       // A-frag: row = lane%16
  const int koff = (lane >> 4) << 3;       // A-frag: k   = (lane/16)*8 + j

  f32x4 acc0 = {0.f, 0.f, 0.f, 0.f};       // cols 0..15
  f32x4 acc1 = {0.f, 0.f, 0.f, 0.f};       // cols 16..31

  if constexpr (ABF16 == 0) {
    const float* ap = (const float*)Av + (size_t)arow * Mdim + koff;
    short* abp = nullptr;
    if constexpr (WRITE_AB) abp = AbOut + (size_t)arow * Mdim + koff;
#pragma unroll 8
    for (int ks = 0; ks < KSTEPS; ++ks) {
      f32x4 a0 = *reinterpret_cast<const f32x4*>(ap);
      f32x4 a1 = *reinterpret_cast<const f32x4*>(ap + 4);
      short8v av;
#pragma unroll
      for (int j = 0; j < 4; ++j) av[j] = bf16r(a0[j]);
#pragma unroll
      for (int j = 0; j < 4; ++j) av[4 + j] = bf16r(a1[j]);
      short8v b0 = Bp[(ks << 1) * 64 + lane];
      short8v b1 = Bp[((ks << 1) + 1) * 64 + lane];
      acc0 = __builtin_amdgcn_mfma_f32_16x16x32_bf16(av, b0, acc0, 0, 0, 0);
      acc1 = __builtin_amdgcn_mfma_f32_16x16x32_bf16(av, b1, acc1, 0, 0, 0);
      if constexpr (WRITE_AB) {
        *reinterpret_cast<short8v*>(abp) = av;
        abp += 32;
      }
      ap += 32;
    }
  } else {
    const short* ap = (const short*)Av + (size_t)arow * Mdim + koff;
#pragma unroll 8
    for (int ks = 0; ks < KSTEPS; ++ks) {
      short8v av = *reinterpret_cast<const short8v*>(ap);
      short8v b0 = Bp[(ks << 1) * 64 + lane];
      short8v b1 = Bp[((ks << 1) + 1) * 64 + lane];
      acc0 = __builtin_amdgcn_mfma_f32_16x16x32_bf16(av, b0, acc0, 0, 0, 0);
      acc1 = __builtin_amdgcn_mfma_f32_16x16x32_bf16(av, b1, acc1, 0, 0, 0);
      ap += 32;
    }
  }

  // ---- epilogue: C/D layout is col = lane&15, row = (lane>>4)*4 + reg (m89) ----
  __shared__ float Cl[16][32];
  const int crow = (lane >> 4) << 2;
  const int ccol = lane & 15;
#pragma unroll
  for (int q = 0; q < 4; ++q) {
    float v0 = acc0[q], v1 = acc1[q];
    if constexpr (HASPREV) {
      v0 = 2.f * v0 - Tprev[(size_t)(r0 + crow + q) * 32 + ccol];
      v1 = 2.f * v1 - Tprev[(size_t)(r0 + crow + q) * 32 + 16 + ccol];
    }
    Cl[crow + q][ccol] = v0;
    Cl[crow + q][16 + ccol] = v1;
  }
  __syncthreads();

  // Tout (f32 row-major): 16x32 tile is contiguous 2 KB in global
  {
    const float* cf = &Cl[0][0];
    f32x4 t0 = *reinterpret_cast<const f32x4*>(cf + lane * 8);
    f32x4 t1 = *reinterpret_cast<const f32x4*>(cf + lane * 8 + 4);
    float* op = Tout + (size_t)r0 * 32 + lane * 8;
    *reinterpret_cast<f32x4*>(op) = t0;
    *reinterpret_cast<f32x4*>(op + 4) = t1;
  }

  // BpOut fragment write: this wave owns half (32 lanes' worth) of group ks=r0/32
  {
    const int ksOut = r0 >> 5;
    const int sub = (r0 >> 4) & 1;          // which half of the 32-row group
    const int h = lane >> 5;                // column half 0/1
    const int lp = (lane & 31) + sub * 32;  // fragment lane we produce
    const int col = h * 16 + (lp & 15);
    const int lrbase = (lp & 16) ? 8 : 0;   // local row base within our 16 rows
    short8v v;
#pragma unroll
    for (int j = 0; j < 8; ++j) v[j] = bf16r(Cl[lrbase + j][col]);
    reinterpret_cast<short8v*>(BpOut)[(ksOut << 1 | h) * 64 + lp] = v;
  }
}

// y[n][o] = sum_k sum_i Xk[n][i] * W[i][o][k],  W: [32][32][7] f32
__global__ __launch_bounds__(256)
void combine(const float* __restrict__ x,
             const float* __restrict__ T1l, const float* __restrict__ T2l,
             const float* __restrict__ T3l, const float* __restrict__ T1u,
             const float* __restrict__ T2u, const float* __restrict__ T3u,
             const float* __restrict__ W, float* __restrict__ y)
{
  __shared__ float Wl[7168];
  for (int i = threadIdx.x; i < 7168; i += 256) Wl[i] = W[i];
  __syncthreads();
  int t = blockIdx.x * 256 + threadIdx.x;
  int n = t >> 5, o = t & 31;
  const float* Xs[7] = {x, T1l, T2l, T3l, T1u, T2u, T3u};
  float sum = 0.f;
#pragma unroll
  for (int k = 0; k < 7; ++k) {
    const f32x4* Xr = reinterpret_cast<const f32x4*>(Xs[k] + (size_t)n * 32);
#pragma unroll
    for (int i4 = 0; i4 < 8; ++i4) {
      f32x4 xv = Xr[i4];
#pragma unroll
      for (int j = 0; j < 4; ++j)
        sum += xv[j] * Wl[(i4 * 4 + j) * 224 + o * 7 + k];
    }
  }
  y[t] = sum;
}

extern "C" void kernel_launch(void* const* d_in, const int* in_sizes, int n_in,
                              void* d_out, int out_size, void* d_ws, size_t ws_size,
                              hipStream_t stream)
{
  const float* x  = (const float*)d_in[0];
  const float* Ll = (const float*)d_in[1];
  const float* Lu = (const float*)d_in[2];
  const float* W  = (const float*)d_in[3];
  float* y = (float*)d_out;

  char* ws = (char*)d_ws;
  size_t off = 0;
  auto alloc = [&](size_t bytes) -> void* {
    void* p = ws + off; off += (bytes + 255) & ~(size_t)255; return p;
  };
  short* Bx  = (short*)alloc(512 * 1024);
  short* Bp0 = (short*)alloc(512 * 1024);
  short* Bp1 = (short*)alloc(512 * 1024);
  float* T1l = (float*)alloc(1u << 20);
  float* T2l = (float*)alloc(1u << 20);
  float* T3l = (float*)alloc(1u << 20);
  float* T1u = (float*)alloc(1u << 20);
  float* T2u = (float*)alloc(1u << 20);
  float* T3u = (float*)alloc(1u << 20);

  const size_t lbytes = (size_t)Mdim * Mdim * sizeof(short);
  bool useBF = (ws_size >= off + 2 * lbytes);
  short* Llb = nullptr; short* Lub = nullptr;
  if (useBF) { Llb = (short*)alloc(lbytes); Lub = (short*)alloc(lbytes); }

  repack_x<<<128, 256, 0, stream>>>(x, Bx);

  if (useBF) {
    // pass 1 converts L to bf16 on the fly and caches it; passes 2-3 read bf16 (L3-resident)
    gemm_pass<0,1,0><<<512,64,0,stream>>>(Ll,  Llb,     (const short8v*)Bx,  nullptr, T1l, Bp0);
    gemm_pass<1,0,1><<<512,64,0,stream>>>(Llb, nullptr, (const short8v*)Bp0, x,       T2l, Bp1);
    gemm_pass<1,0,1><<<512,64,0,stream>>>(Llb, nullptr, (const short8v*)Bp1, T1l,     T3l, Bp0);
    gemm_pass<0,1,0><<<512,64,0,stream>>>(Lu,  Lub,     (const short8v*)Bx,  nullptr, T1u, Bp0);
    gemm_pass<1,0,1><<<512,64,0,stream>>>(Lub, nullptr, (const short8v*)Bp0, x,       T2u, Bp1);
    gemm_pass<1,0,1><<<512,64,0,stream>>>(Lub, nullptr, (const short8v*)Bp1, T1u,     T3u, Bp0);
  } else {
    gemm_pass<0,0,0><<<512,64,0,stream>>>(Ll, nullptr, (const short8v*)Bx,  nullptr, T1l, Bp0);
    gemm_pass<0,0,1><<<512,64,0,stream>>>(Ll, nullptr, (const short8v*)Bp0, x,       T2l, Bp1);
    gemm_pass<0,0,1><<<512,64,0,stream>>>(Ll, nullptr, (const short8v*)Bp1, T1l,     T3l, Bp0);
    gemm_pass<0,0,0><<<512,64,0,stream>>>(Lu, nullptr, (const short8v*)Bx,  nullptr, T1u, Bp0);
    gemm_pass<0,0,1><<<512,64,0,stream>>>(Lu, nullptr, (const short8v*)Bp0, x,       T2u, Bp1);
    gemm_pass<0,0,1><<<512,64,0,stream>>>(Lu, nullptr, (const short8v*)Bp1, T1u,     T3u, Bp0);
  }

  combine<<<1024, 256, 0, stream>>>(x, T1l, T2l, T3l, T1u, T2u, T3u, W, y);
}

// Round 2
// 373.680 us; speedup vs baseline: 1.3709x; 1.3709x over previous
//
#include <hip/hip_runtime.h>
#include <hip/hip_bf16.h>
#include <stdint.h>

#define Mdim 8192
#define KSTEPS 256        // 8192 / 32
#define KSTEPS_W 64       // per-wave k-steps (KSTEPS / 4 waves)

typedef __attribute__((ext_vector_type(8))) short short8v;  // 8 bf16 (4 VGPRs)
typedef __attribute__((ext_vector_type(4))) float f32x4;
typedef __attribute__((ext_vector_type(2))) float f32x2;

// round-to-nearest-even f32 -> bf16 (finite inputs)
static __device__ __forceinline__ short bf16r(float f) {
  union { float f; uint32_t u; } c; c.f = f;
  uint32_t u = c.u;
  uint32_t r = (u + 0x7fffu + ((u >> 16) & 1u)) >> 16;
  return (short)(r & 0xffffu);
}

// Repack x (f32 [8192][32]) into MFMA B-fragment layout:
// Bp[((ks*2 + h)*64 + lane)*8 + j] = bf16( B[ks*32 + (lane>>4)*8 + j][h*16 + (lane&15)] )
__global__ __launch_bounds__(256)
void repack_x(const float* __restrict__ x, short* __restrict__ Bp)
{
  int t = blockIdx.x * 256 + threadIdx.x;       // 32768 threads total
  int l = t & 63, h = (t >> 6) & 1, ks = t >> 7;
  int col = h * 16 + (l & 15);
  int kbase = ks * 32 + ((l >> 4) << 3);
  short8v v;
#pragma unroll
  for (int j = 0; j < 8; ++j) v[j] = bf16r(x[(size_t)(kbase + j) * 32 + col]);
  reinterpret_cast<short8v*>(Bp)[t] = v;
}

// One Chebyshev GEMM pass: Tout = (A @ B)            (HASPREV=0)
//                       or Tout = 2*(A @ B) - Tprev  (HASPREV=1)
// A: [8192][8192] f32 (ABF16=0) or bf16-as-short (ABF16=1), row-major.
// B: fragment-packed bf16 (see repack_x).
// Also emits BpOut = fragment-packed bf16 of Tout (next pass's B input),
// and (WRITE_AB) a bf16 copy of A for later passes.
// Grid: 512 blocks x 256 threads. Block = one 16-row output tile;
// 4 waves K-split (2048 each), partials reduced through LDS.
template<int ABF16, int WRITE_AB, int HASPREV>
__global__ __launch_bounds__(256)
void gemm_pass(const void* __restrict__ Av,
               short* __restrict__ AbOut,
               const short8v* __restrict__ Bp,
               const float* __restrict__ Tprev,
               float* __restrict__ Tout,
               short* __restrict__ BpOut)
{
  const int lane = threadIdx.x & 63;
  const int wid  = threadIdx.x >> 6;         // wave id 0..3 -> K chunk
  const int r0 = blockIdx.x << 4;            // first output row of this tile
  const int arow = r0 + (lane & 15);         // A-frag: row = lane%16
  const int koff = (lane >> 4) << 3;         // A-frag: k   = (lane/16)*8 + j
  const int ksbase = wid * KSTEPS_W;         // this wave's first k-step

  f32x4 acc0 = {0.f, 0.f, 0.f, 0.f};         // cols 0..15
  f32x4 acc1 = {0.f, 0.f, 0.f, 0.f};         // cols 16..31

  if constexpr (ABF16 == 0) {
    const float* ap = (const float*)Av + (size_t)arow * Mdim + ksbase * 32 + koff;
    short* abp = nullptr;
    if constexpr (WRITE_AB) abp = AbOut + (size_t)arow * Mdim + ksbase * 32 + koff;
#pragma unroll 8
    for (int ks = 0; ks < KSTEPS_W; ++ks) {
      const int g = ksbase + ks;
      f32x4 a0 = *reinterpret_cast<const f32x4*>(ap);
      f32x4 a1 = *reinterpret_cast<const f32x4*>(ap + 4);
      short8v av;
#pragma unroll
      for (int j = 0; j < 4; ++j) av[j] = bf16r(a0[j]);
#pragma unroll
      for (int j = 0; j < 4; ++j) av[4 + j] = bf16r(a1[j]);
      short8v b0 = Bp[(g << 1) * 64 + lane];
      short8v b1 = Bp[((g << 1) + 1) * 64 + lane];
      acc0 = __builtin_amdgcn_mfma_f32_16x16x32_bf16(av, b0, acc0, 0, 0, 0);
      acc1 = __builtin_amdgcn_mfma_f32_16x16x32_bf16(av, b1, acc1, 0, 0, 0);
      if constexpr (WRITE_AB) {
        *reinterpret_cast<short8v*>(abp) = av;
        abp += 32;
      }
      ap += 32;
    }
  } else {
    const short* ap = (const short*)Av + (size_t)arow * Mdim + ksbase * 32 + koff;
#pragma unroll 8
    for (int ks = 0; ks < KSTEPS_W; ++ks) {
      const int g = ksbase + ks;
      short8v av = *reinterpret_cast<const short8v*>(ap);
      short8v b0 = Bp[(g << 1) * 64 + lane];
      short8v b1 = Bp[((g << 1) + 1) * 64 + lane];
      acc0 = __builtin_amdgcn_mfma_f32_16x16x32_bf16(av, b0, acc0, 0, 0, 0);
      acc1 = __builtin_amdgcn_mfma_f32_16x16x32_bf16(av, b1, acc1, 0, 0, 0);
      ap += 32;
    }
  }

  // ---- per-wave partials -> LDS ----
  // C/D layout: col = lane&15, row = (lane>>4)*4 + reg  (m89-verified)
  __shared__ float Cl[4][16][32];   // 8 KB partials
  __shared__ float Cred[16][32];    // 2 KB reduced tile
  {
    const int crow = (lane >> 4) << 2;
    const int ccol = lane & 15;
#pragma unroll
    for (int q = 0; q < 4; ++q) {
      Cl[wid][crow + q][ccol] = acc0[q];
      Cl[wid][crow + q][16 + ccol] = acc1[q];
    }
  }
  __syncthreads();

  // ---- reduce 4 partials + Chebyshev recurrence + Tout write ----
  // thread t handles flat elems 2t, 2t+1 of the 16x32 tile
  {
    const int t = threadIdx.x;
    const int e = t * 2;
    const int row = e >> 5, col = e & 31;
    float v0 = Cl[0][row][col] + Cl[1][row][col] + Cl[2][row][col] + Cl[3][row][col];
    float v1 = Cl[0][row][col + 1] + Cl[1][row][col + 1] + Cl[2][row][col + 1] + Cl[3][row][col + 1];
    if constexpr (HASPREV) {
      f32x2 p = *reinterpret_cast<const f32x2*>(Tprev + (size_t)r0 * 32 + e);
      v0 = 2.f * v0 - p[0];
      v1 = 2.f * v1 - p[1];
    }
    f32x2 o; o[0] = v0; o[1] = v1;
    *reinterpret_cast<f32x2*>(Tout + (size_t)r0 * 32 + e) = o;
    Cred[row][col] = v0;
    Cred[row][col + 1] = v1;
  }
  __syncthreads();

  // ---- BpOut fragment write: 64 short8v entries for this 16-row tile ----
  if (threadIdx.x < 64) {
    const int t = threadIdx.x;
    const int ksOut = r0 >> 5;
    const int sub = (r0 >> 4) & 1;          // which half of the 32-row group
    const int h = t >> 5;                   // column half 0/1
    const int lp = (t & 31) + sub * 32;     // fragment lane we produce
    const int col = h * 16 + (lp & 15);
    const int lrbase = (lp & 16) ? 8 : 0;   // local row base within our 16 rows
    short8v v;
#pragma unroll
    for (int j = 0; j < 8; ++j) v[j] = bf16r(Cred[lrbase + j][col]);
    reinterpret_cast<short8v*>(BpOut)[(ksOut << 1 | h) * 64 + lp] = v;
  }
}

// y[n][o] = sum_k sum_i Xk[n][i] * W[i][o][k],  W: [32][32][7] f32
__global__ __launch_bounds__(256)
void combine(const float* __restrict__ x,
             const float* __restrict__ T1l, const float* __restrict__ T2l,
             const float* __restrict__ T3l, const float* __restrict__ T1u,
             const float* __restrict__ T2u, const float* __restrict__ T3u,
             const float* __restrict__ W, float* __restrict__ y)
{
  __shared__ float Wl[7168];
  for (int i = threadIdx.x; i < 7168; i += 256) Wl[i] = W[i];
  __syncthreads();
  int t = blockIdx.x * 256 + threadIdx.x;
  int n = t >> 5, o = t & 31;
  const float* Xs[7] = {x, T1l, T2l, T3l, T1u, T2u, T3u};
  float sum = 0.f;
#pragma unroll
  for (int k = 0; k < 7; ++k) {
    const f32x4* Xr = reinterpret_cast<const f32x4*>(Xs[k] + (size_t)n * 32);
#pragma unroll
    for (int i4 = 0; i4 < 8; ++i4) {
      f32x4 xv = Xr[i4];
#pragma unroll
      for (int j = 0; j < 4; ++j)
        sum += xv[j] * Wl[(i4 * 4 + j) * 224 + o * 7 + k];
    }
  }
  y[t] = sum;
}

extern "C" void kernel_launch(void* const* d_in, const int* in_sizes, int n_in,
                              void* d_out, int out_size, void* d_ws, size_t ws_size,
                              hipStream_t stream)
{
  const float* x  = (const float*)d_in[0];
  const float* Ll = (const float*)d_in[1];
  const float* Lu = (const float*)d_in[2];
  const float* W  = (const float*)d_in[3];
  float* y = (float*)d_out;

  char* ws = (char*)d_ws;
  size_t off = 0;
  auto alloc = [&](size_t bytes) -> void* {
    void* p = ws + off; off += (bytes + 255) & ~(size_t)255; return p;
  };
  short* Bx  = (short*)alloc(512 * 1024);
  short* Bp0 = (short*)alloc(512 * 1024);
  short* Bp1 = (short*)alloc(512 * 1024);
  float* T1l = (float*)alloc(1u << 20);
  float* T2l = (float*)alloc(1u << 20);
  float* T3l = (float*)alloc(1u << 20);
  float* T1u = (float*)alloc(1u << 20);
  float* T2u = (float*)alloc(1u << 20);
  float* T3u = (float*)alloc(1u << 20);

  const size_t lbytes = (size_t)Mdim * Mdim * sizeof(short);
  bool useBF = (ws_size >= off + 2 * lbytes);
  short* Llb = nullptr; short* Lub = nullptr;
  if (useBF) { Llb = (short*)alloc(lbytes); Lub = (short*)alloc(lbytes); }

  repack_x<<<128, 256, 0, stream>>>(x, Bx);

  if (useBF) {
    // pass 1 converts L to bf16 on the fly and caches it; passes 2-3 read bf16 (L3-assisted)
    gemm_pass<0,1,0><<<512,256,0,stream>>>(Ll,  Llb,     (const short8v*)Bx,  nullptr, T1l, Bp0);
    gemm_pass<1,0,1><<<512,256,0,stream>>>(Llb, nullptr, (const short8v*)Bp0, x,       T2l, Bp1);
    gemm_pass<1,0,1><<<512,256,0,stream>>>(Llb, nullptr, (const short8v*)Bp1, T1l,     T3l, Bp0);
    gemm_pass<0,1,0><<<512,256,0,stream>>>(Lu,  Lub,     (const short8v*)Bx,  nullptr, T1u, Bp0);
    gemm_pass<1,0,1><<<512,256,0,stream>>>(Lub, nullptr, (const short8v*)Bp0, x,       T2u, Bp1);
    gemm_pass<1,0,1><<<512,256,0,stream>>>(Lub, nullptr, (const short8v*)Bp1, T1u,     T3u, Bp0);
  } else {
    gemm_pass<0,0,0><<<512,256,0,stream>>>(Ll, nullptr, (const short8v*)Bx,  nullptr, T1l, Bp0);
    gemm_pass<0,0,1><<<512,256,0,stream>>>(Ll, nullptr, (const short8v*)Bp0, x,       T2l, Bp1);
    gemm_pass<0,0,1><<<512,256,0,stream>>>(Ll, nullptr, (const short8v*)Bp1, T1l,     T3l, Bp0);
    gemm_pass<0,0,0><<<512,256,0,stream>>>(Lu, nullptr, (const short8v*)Bx,  nullptr, T1u, Bp0);
    gemm_pass<0,0,1><<<512,256,0,stream>>>(Lu, nullptr, (const short8v*)Bp0, x,       T2u, Bp1);
    gemm_pass<0,0,1><<<512,256,0,stream>>>(Lu, nullptr, (const short8v*)Bp1, T1u,     T3u, Bp0);
  }

  combine<<<1024, 256, 0, stream>>>(x, T1l, T2l, T3l, T1u, T2u, T3u, W, y);
}

// Round 3
// 365.408 us; speedup vs baseline: 1.4019x; 1.0226x over previous
//
#include <hip/hip_runtime.h>
#include <hip/hip_bf16.h>
#include <stdint.h>

#define Mdim 8192
#define KSTEPS 256        // 8192 / 32
#define NWAVES 8
#define KSTEPS_W (KSTEPS / NWAVES)   // 32 k-steps per wave

typedef __attribute__((ext_vector_type(8))) short short8v;  // 8 bf16 (4 VGPRs)
typedef __attribute__((ext_vector_type(4))) float f32x4;

// f32 -> bf16 via standard cast; compiler emits v_cvt_pk_bf16_f32 pairs (m240)
static __device__ __forceinline__ short bf16c(float f) {
  __hip_bfloat16 h = __float2bfloat16(f);
  union { __hip_bfloat16 h; short s; } c; c.h = h;
  return c.s;
}

// Repack x (f32 [8192][32]) into MFMA B-fragment layout:
// Bp[((ks*2 + h)*64 + lane)*8 + j] = bf16( B[ks*32 + (lane>>4)*8 + j][h*16 + (lane&15)] )
__global__ __launch_bounds__(256)
void repack_x(const float* __restrict__ x, short* __restrict__ Bp)
{
  int t = blockIdx.x * 256 + threadIdx.x;       // 32768 threads total
  int l = t & 63, h = (t >> 6) & 1, ks = t >> 7;
  int col = h * 16 + (l & 15);
  int kbase = ks * 32 + ((l >> 4) << 3);
  short8v v;
#pragma unroll
  for (int j = 0; j < 8; ++j) v[j] = bf16c(x[(size_t)(kbase + j) * 32 + col]);
  reinterpret_cast<short8v*>(Bp)[t] = v;
}

// Fused Chebyshev GEMM stage for BOTH chains (Ll and Lu):
//   blocks 0..511  -> chain 0 (l), rows 16*b
//   blocks 512..1023 -> chain 1 (u), rows 16*(b-512)
// Tout = (A @ B)            (HASPREV=0)
// Tout = 2*(A @ B) - Tprev  (HASPREV=1)
// A: f32 (ABF16=0) or bf16-as-short (ABF16=1), row-major [8192][8192].
// B: fragment-packed bf16. Emits BpOut (next stage's B) and optionally
// a bf16 copy of A (WRITE_AB, stage 1 only).
// Block: 512 threads = 8 waves, K-split 8 x 1024, LDS reduction.
template<int ABF16, int WRITE_AB, int HASPREV>
__global__ __launch_bounds__(512)
void gemm_stage(const void* __restrict__ Al, const void* __restrict__ Au,
                short* __restrict__ AbOutL, short* __restrict__ AbOutU,
                const short8v* __restrict__ BpL, const short8v* __restrict__ BpU,
                const float* __restrict__ TprevL, const float* __restrict__ TprevU,
                float* __restrict__ ToutL, float* __restrict__ ToutU,
                short* __restrict__ BpOutL, short* __restrict__ BpOutU)
{
  const int chain = blockIdx.x >> 9;
  const void* Av = chain ? Au : Al;
  short* AbOut = chain ? AbOutU : AbOutL;
  const short8v* Bp = chain ? BpU : BpL;
  const float* Tprev = chain ? TprevU : TprevL;
  float* Tout = chain ? ToutU : ToutL;
  short* BpOut = chain ? BpOutU : BpOutL;

  const int lane = threadIdx.x & 63;
  const int wid  = threadIdx.x >> 6;         // wave id 0..7 -> K chunk
  const int r0 = (blockIdx.x & 511) << 4;    // first output row of this tile
  const int arow = r0 + (lane & 15);         // A-frag: row = lane%16
  const int koff = (lane >> 4) << 3;         // A-frag: k   = (lane/16)*8 + j
  const int ksbase = wid * KSTEPS_W;         // this wave's first k-step

  f32x4 acc0 = {0.f, 0.f, 0.f, 0.f};         // cols 0..15
  f32x4 acc1 = {0.f, 0.f, 0.f, 0.f};         // cols 16..31

  if constexpr (ABF16 == 0) {
    const float* ap = (const float*)Av + (size_t)arow * Mdim + ksbase * 32 + koff;
    short* abp = nullptr;
    if constexpr (WRITE_AB) abp = AbOut + (size_t)arow * Mdim + ksbase * 32 + koff;
#pragma unroll 8
    for (int ks = 0; ks < KSTEPS_W; ++ks) {
      const int g = ksbase + ks;
      f32x4 a0 = *reinterpret_cast<const f32x4*>(ap);
      f32x4 a1 = *reinterpret_cast<const f32x4*>(ap + 4);
      short8v av;
#pragma unroll
      for (int j = 0; j < 4; ++j) av[j] = bf16c(a0[j]);
#pragma unroll
      for (int j = 0; j < 4; ++j) av[4 + j] = bf16c(a1[j]);
      short8v b0 = Bp[(g << 1) * 64 + lane];
      short8v b1 = Bp[((g << 1) + 1) * 64 + lane];
      acc0 = __builtin_amdgcn_mfma_f32_16x16x32_bf16(av, b0, acc0, 0, 0, 0);
      acc1 = __builtin_amdgcn_mfma_f32_16x16x32_bf16(av, b1, acc1, 0, 0, 0);
      if constexpr (WRITE_AB) {
        *reinterpret_cast<short8v*>(abp) = av;
        abp += 32;
      }
      ap += 32;
    }
  } else {
    const short* ap = (const short*)Av + (size_t)arow * Mdim + ksbase * 32 + koff;
#pragma unroll 8
    for (int ks = 0; ks < KSTEPS_W; ++ks) {
      const int g = ksbase + ks;
      short8v av = *reinterpret_cast<const short8v*>(ap);
      short8v b0 = Bp[(g << 1) * 64 + lane];
      short8v b1 = Bp[((g << 1) + 1) * 64 + lane];
      acc0 = __builtin_amdgcn_mfma_f32_16x16x32_bf16(av, b0, acc0, 0, 0, 0);
      acc1 = __builtin_amdgcn_mfma_f32_16x16x32_bf16(av, b1, acc1, 0, 0, 0);
      ap += 32;
    }
  }

  // ---- per-wave partials -> LDS ----
  // C/D layout: col = lane&15, row = (lane>>4)*4 + reg  (m89-verified)
  __shared__ float Cl[NWAVES][16][32];   // 16 KB partials
  __shared__ float Cred[16][32];         // 2 KB reduced tile
  {
    const int crow = (lane >> 4) << 2;
    const int ccol = lane & 15;
#pragma unroll
    for (int q = 0; q < 4; ++q) {
      Cl[wid][crow + q][ccol] = acc0[q];
      Cl[wid][crow + q][16 + ccol] = acc1[q];
    }
  }
  __syncthreads();

  // ---- reduce 8 partials + Chebyshev recurrence + Tout write ----
  // thread t handles flat elem t of the 16x32 tile
  {
    const int t = threadIdx.x;
    const int row = t >> 5, col = t & 31;
    float v = Cl[0][row][col] + Cl[1][row][col] + Cl[2][row][col] + Cl[3][row][col]
            + Cl[4][row][col] + Cl[5][row][col] + Cl[6][row][col] + Cl[7][row][col];
    if constexpr (HASPREV) {
      v = 2.f * v - Tprev[(size_t)r0 * 32 + t];
    }
    Tout[(size_t)r0 * 32 + t] = v;
    Cred[row][col] = v;
  }
  __syncthreads();

  // ---- BpOut fragment write: 64 short8v entries for this 16-row tile ----
  if (threadIdx.x < 64) {
    const int t = threadIdx.x;
    const int ksOut = r0 >> 5;
    const int sub = (r0 >> 4) & 1;          // which half of the 32-row group
    const int h = t >> 5;                   // column half 0/1
    const int lp = (t & 31) + sub * 32;     // fragment lane we produce
    const int col = h * 16 + (lp & 15);
    const int lrbase = (lp & 16) ? 8 : 0;   // local row base within our 16 rows
    short8v v;
#pragma unroll
    for (int j = 0; j < 8; ++j) v[j] = bf16c(Cred[lrbase + j][col]);
    reinterpret_cast<short8v*>(BpOut)[(ksOut << 1 | h) * 64 + lp] = v;
  }
}

// y[n][o] = sum_k sum_i Xk[n][i] * W[i][o][k],  W: [32][32][7] f32
__global__ __launch_bounds__(256)
void combine(const float* __restrict__ x,
             const float* __restrict__ T1l, const float* __restrict__ T2l,
             const float* __restrict__ T3l, const float* __restrict__ T1u,
             const float* __restrict__ T2u, const float* __restrict__ T3u,
             const float* __restrict__ W, float* __restrict__ y)
{
  __shared__ float Wl[7168];
  for (int i = threadIdx.x; i < 7168; i += 256) Wl[i] = W[i];
  __syncthreads();
  int t = blockIdx.x * 256 + threadIdx.x;
  int n = t >> 5, o = t & 31;
  const float* Xs[7] = {x, T1l, T2l, T3l, T1u, T2u, T3u};
  float sum = 0.f;
#pragma unroll
  for (int k = 0; k < 7; ++k) {
    const f32x4* Xr = reinterpret_cast<const f32x4*>(Xs[k] + (size_t)n * 32);
#pragma unroll
    for (int i4 = 0; i4 < 8; ++i4) {
      f32x4 xv = Xr[i4];
#pragma unroll
      for (int j = 0; j < 4; ++j)
        sum += xv[j] * Wl[(i4 * 4 + j) * 224 + o * 7 + k];
    }
  }
  y[t] = sum;
}

extern "C" void kernel_launch(void* const* d_in, const int* in_sizes, int n_in,
                              void* d_out, int out_size, void* d_ws, size_t ws_size,
                              hipStream_t stream)
{
  const float* x  = (const float*)d_in[0];
  const float* Ll = (const float*)d_in[1];
  const float* Lu = (const float*)d_in[2];
  const float* W  = (const float*)d_in[3];
  float* y = (float*)d_out;

  char* ws = (char*)d_ws;
  size_t off = 0;
  auto alloc = [&](size_t bytes) -> void* {
    void* p = ws + off; off += (bytes + 255) & ~(size_t)255; return p;
  };
  short* Bx  = (short*)alloc(512 * 1024);
  short* Bl1 = (short*)alloc(512 * 1024);
  short* Bl2 = (short*)alloc(512 * 1024);
  short* Bu1 = (short*)alloc(512 * 1024);
  short* Bu2 = (short*)alloc(512 * 1024);
  float* T1l = (float*)alloc(1u << 20);
  float* T2l = (float*)alloc(1u << 20);
  float* T3l = (float*)alloc(1u << 20);
  float* T1u = (float*)alloc(1u << 20);
  float* T2u = (float*)alloc(1u << 20);
  float* T3u = (float*)alloc(1u << 20);

  const size_t lbytes = (size_t)Mdim * Mdim * sizeof(short);
  bool useBF = (ws_size >= off + 2 * lbytes);
  short* Llb = nullptr; short* Lub = nullptr;
  if (useBF) { Llb = (short*)alloc(lbytes); Lub = (short*)alloc(lbytes); }

  repack_x<<<128, 256, 0, stream>>>(x, Bx);

  if (useBF) {
    // stage 1 converts L->bf16 on the fly and caches it; stages 2-3 read bf16
    gemm_stage<0,1,0><<<1024,512,0,stream>>>(Ll, Lu, Llb, Lub,
        (const short8v*)Bx, (const short8v*)Bx, nullptr, nullptr,
        T1l, T1u, Bl1, Bu1);
    gemm_stage<1,0,1><<<1024,512,0,stream>>>(Llb, Lub, nullptr, nullptr,
        (const short8v*)Bl1, (const short8v*)Bu1, x, x,
        T2l, T2u, Bl2, Bu2);
    gemm_stage<1,0,1><<<1024,512,0,stream>>>(Llb, Lub, nullptr, nullptr,
        (const short8v*)Bl2, (const short8v*)Bu2, T1l, T1u,
        T3l, T3u, Bl1, Bu1);
  } else {
    gemm_stage<0,0,0><<<1024,512,0,stream>>>(Ll, Lu, nullptr, nullptr,
        (const short8v*)Bx, (const short8v*)Bx, nullptr, nullptr,
        T1l, T1u, Bl1, Bu1);
    gemm_stage<0,0,1><<<1024,512,0,stream>>>(Ll, Lu, nullptr, nullptr,
        (const short8v*)Bl1, (const short8v*)Bu1, x, x,
        T2l, T2u, Bl2, Bu2);
    gemm_stage<0,0,1><<<1024,512,0,stream>>>(Ll, Lu, nullptr, nullptr,
        (const short8v*)Bl2, (const short8v*)Bu2, T1l, T1u,
        T3l, T3u, Bl1, Bu1);
  }

  combine<<<1024, 256, 0, stream>>>(x, T1l, T2l, T3l, T1u, T2u, T3u, W, y);
}